// Round 7
// baseline (359.568 us; speedup 1.0000x reference)
//
#include <hip/hip_runtime.h>
#include <math.h>

#define NN   50000
#define NE   800000
#define NG   500
#define FIN  80
#define FOUT 40
#define HH   20
#define NC   5

// -------- workspace layout (float offsets) --------
#define OFF_DEG    0
#define OFF_CNT    50000
#define OFF_POOLED 100000
#define OFF_PRE    120000
#define OFF_SEQ    130000
#define OFF_ROWPTR 140000
#define OFF_REC    190004          // uint2[NE] = 2*NE floats; byte off %8==0
#define OFF_Y      1790004         // byte off %16==0

// fast tanh: 1 - 2/(exp2(2*log2e*x)+1); exact saturation at +-inf
__device__ __forceinline__ float tanh_fast(float x) {
    float e;
    asm("v_exp_f32 %0, %1" : "=v"(e) : "v"(x * 2.8853900817779268f));
    float r;
    asm("v_rcp_f32 %0, %1" : "=v"(r) : "v"(e + 1.0f));
    return fmaf(-2.0f, r, 1.0f);
}

__device__ __forceinline__ float bcast_lane(float v, int k) {
    return __uint_as_float(__builtin_amdgcn_readlane(__float_as_uint(v), k));
}

// ---- deg[src] += w ; cnt[dst] += 1 ----
__global__ void k_degcnt(const int* __restrict__ ei, const float* __restrict__ w,
                         float* __restrict__ deg, unsigned int* __restrict__ cnt) {
    int e = blockIdx.x * 256 + threadIdx.x;
    if (e < NE) {
        atomicAdd(&deg[ei[e]], w[e]);
        atomicAdd(&cnt[ei[NE + e]], 1u);
    }
}

// ---- dinv = deg>0 ? rsqrt(deg) : 0 (in place) ----
__global__ void k_dinv(float* __restrict__ deg) {
    int n = blockIdx.x * 256 + threadIdx.x;
    if (n < NN) {
        float d = deg[n];
        deg[n] = (d > 0.f) ? rsqrtf(d) : 0.f;
    }
}

// ---- exclusive scan of cnt -> rowptr; cnt := exclusive prefix (fill cursor) ----
__global__ void k_scanptr(unsigned int* __restrict__ cnt, unsigned int* __restrict__ rowptr) {
    __shared__ unsigned int tot[1024];
    int tid = threadIdx.x;
    bool act = tid < 1000;
    int beg = tid * 50;
    unsigned int vals[50];
    if (act) {
        const uint2* c2 = reinterpret_cast<const uint2*>(cnt + beg);
        #pragma unroll
        for (int j = 0; j < 25; ++j) {
            uint2 v = c2[j];
            vals[j * 2 + 0] = v.x;
            vals[j * 2 + 1] = v.y;
        }
    }
    unsigned int s = 0;
    if (act) {
        #pragma unroll
        for (int j = 0; j < 50; ++j) s += vals[j];
    }
    tot[tid] = s;
    __syncthreads();
    for (int off = 1; off < 1024; off <<= 1) {
        unsigned int t = (tid >= off) ? tot[tid - off] : 0u;
        __syncthreads();
        tot[tid] += t;
        __syncthreads();
    }
    unsigned int base = (tid > 0) ? tot[tid - 1] : 0u;
    if (act) {
        #pragma unroll
        for (int j = 0; j < 50; ++j) {
            unsigned int v = vals[j];
            vals[j] = base;
            base += v;
        }
        uint2* r2 = reinterpret_cast<uint2*>(rowptr + beg);
        uint2* cw = reinterpret_cast<uint2*>(cnt + beg);
        #pragma unroll
        for (int j = 0; j < 25; ++j) {
            uint2 o = make_uint2(vals[j * 2 + 0], vals[j * 2 + 1]);
            r2[j] = o;
            cw[j] = o;
        }
    }
    if (tid == 1023) rowptr[NN] = tot[1023];
}

// ---- y = x @ W1 : thread per (node, 4-col chunk) ----
__global__ void k_y(const float* __restrict__ x, const float* __restrict__ W1,
                    float* __restrict__ y) {
    int gid = blockIdx.x * 256 + threadIdx.x;
    if (gid >= NN * 10) return;
    int n = gid / 10;
    int c = gid % 10;
    const float* xr = x + (size_t)n * FIN;
    float a0 = 0.f, a1 = 0.f, a2 = 0.f, a3 = 0.f;
    #pragma unroll 8
    for (int f = 0; f < FIN; ++f) {
        float xf = xr[f];
        const float4 wv = *reinterpret_cast<const float4*>(W1 + f * FOUT + c * 4);
        a0 = fmaf(xf, wv.x, a0); a1 = fmaf(xf, wv.y, a1);
        a2 = fmaf(xf, wv.z, a2); a3 = fmaf(xf, wv.w, a3);
    }
    float4* yo = reinterpret_cast<float4*>(y) + gid;
    *yo = make_float4(a0, a1, a2, a3);
}

// ---- fill CSR records: rec[pos] = {src, bits(-dinv[s]*w*dinv[d])} ----
__global__ void k_fill(const int* __restrict__ ei, const float* __restrict__ w,
                       const float* __restrict__ dinv, unsigned int* __restrict__ cursor,
                       uint2* __restrict__ rec) {
    int e = blockIdx.x * 256 + threadIdx.x;
    if (e >= NE) return;
    int s = ei[e];
    int d = ei[NE + e];
    float nm = -dinv[s] * w[e] * dinv[d];
    unsigned int pos = atomicAdd(&cursor[d], 1u);
    rec[pos] = make_uint2((unsigned int)s, __float_as_uint(nm));
}

// ---- gather z = sum norm*y[src]; h = relu(x@W0 + b + z); pooled[g] += h ----
// 4-wide edge unroll: 4 independent record loads + 4 independent y gathers
// in flight per iteration (breaks the serial dependent-load chain).
__global__ void k_gather_h(const unsigned int* __restrict__ rowptr,
                           const uint2* __restrict__ rec,
                           const float* __restrict__ y,
                           const float* __restrict__ x,
                           const float* __restrict__ W0,
                           const float* __restrict__ bconv,
                           const int* __restrict__ batch,
                           float* __restrict__ pooled) {
    int gid = blockIdx.x * 256 + threadIdx.x;
    if (gid >= NN * 10) return;
    int n = gid / 10;
    int c = gid % 10;
    unsigned int beg = rowptr[n], end = rowptr[n + 1];
    float z0 = 0.f, z1 = 0.f, z2 = 0.f, z3 = 0.f;
    const float4* y4 = reinterpret_cast<const float4*>(y);
    unsigned int k = beg;
    for (; k + 4 <= end; k += 4) {
        uint2 r0 = rec[k + 0];
        uint2 r1 = rec[k + 1];
        uint2 r2 = rec[k + 2];
        uint2 r3 = rec[k + 3];
        float4 yv0 = y4[r0.x * 10 + c];
        float4 yv1 = y4[r1.x * 10 + c];
        float4 yv2 = y4[r2.x * 10 + c];
        float4 yv3 = y4[r3.x * 10 + c];
        float n0 = __uint_as_float(r0.y), n1 = __uint_as_float(r1.y);
        float n2 = __uint_as_float(r2.y), n3 = __uint_as_float(r3.y);
        z0 = fmaf(n0, yv0.x, z0); z1 = fmaf(n0, yv0.y, z1);
        z2 = fmaf(n0, yv0.z, z2); z3 = fmaf(n0, yv0.w, z3);
        z0 = fmaf(n1, yv1.x, z0); z1 = fmaf(n1, yv1.y, z1);
        z2 = fmaf(n1, yv1.z, z2); z3 = fmaf(n1, yv1.w, z3);
        z0 = fmaf(n2, yv2.x, z0); z1 = fmaf(n2, yv2.y, z1);
        z2 = fmaf(n2, yv2.z, z2); z3 = fmaf(n2, yv2.w, z3);
        z0 = fmaf(n3, yv3.x, z0); z1 = fmaf(n3, yv3.y, z1);
        z2 = fmaf(n3, yv3.z, z2); z3 = fmaf(n3, yv3.w, z3);
    }
    for (; k < end; ++k) {
        uint2 r = rec[k];
        float nm = __uint_as_float(r.y);
        float4 yv = y4[r.x * 10 + c];
        z0 = fmaf(nm, yv.x, z0); z1 = fmaf(nm, yv.y, z1);
        z2 = fmaf(nm, yv.z, z2); z3 = fmaf(nm, yv.w, z3);
    }
    const float4 bv = *reinterpret_cast<const float4*>(bconv + c * 4);
    float a0 = bv.x, a1 = bv.y, a2 = bv.z, a3 = bv.w;
    const float* xr = x + (size_t)n * FIN;
    #pragma unroll 8
    for (int f = 0; f < FIN; ++f) {
        float xf = xr[f];
        const float4 wv = *reinterpret_cast<const float4*>(W0 + f * FOUT + c * 4);
        a0 = fmaf(xf, wv.x, a0); a1 = fmaf(xf, wv.y, a1);
        a2 = fmaf(xf, wv.z, a2); a3 = fmaf(xf, wv.w, a3);
    }
    float h0 = fmaxf(a0 + z0, 0.f);
    float h1 = fmaxf(a1 + z1, 0.f);
    float h2 = fmaxf(a2 + z2, 0.f);
    float h3 = fmaxf(a3 + z3, 0.f);
    float* p = pooled + (size_t)batch[n] * FOUT + c * 4;
    atomicAdd(p + 0, h0);
    atomicAdd(p + 1, h1);
    atomicAdd(p + 2, h2);
    atomicAdd(p + 3, h3);
}

// ---- pre[t][j] = pooled[t]·W_ih[j] + b_ih[j] + b_hh[j] ----
__global__ void k_pre(const float* __restrict__ pooled, const float* __restrict__ Wih,
                      const float* __restrict__ bih, const float* __restrict__ bhh,
                      float* __restrict__ pre) {
    int gid = blockIdx.x * 256 + threadIdx.x;
    if (gid >= NG * HH) return;
    int t = gid / HH;
    int j = gid % HH;
    float acc = bih[j] + bhh[j];
    #pragma unroll
    for (int f = 0; f < FOUT; ++f)
        acc = fmaf(pooled[t * FOUT + f], Wih[j * FOUT + f], acc);
    pre[gid] = acc;
}

// ---- serial scan: h_t = tanh(pre_t + W_hh h_{t-1}) ; single wave ----
__global__ void k_scan(const float* __restrict__ pre, const float* __restrict__ Whh,
                       float* __restrict__ seq) {
    __shared__ float spre[NG * HH];          // 40 KB
    int lane = threadIdx.x;
    const float4* p4 = reinterpret_cast<const float4*>(pre);
    float4* s4 = reinterpret_cast<float4*>(spre);
    #pragma unroll
    for (int j = 0; j < 40; ++j) {
        int idx = j * 64 + lane;
        if (idx < NG * HH / 4) s4[idx] = p4[idx];
    }
    float whh[HH];
    #pragma unroll
    for (int k = 0; k < HH; ++k)
        whh[k] = (lane < HH) ? Whh[lane * HH + k] : 0.f;
    __syncthreads();
    int myoff = (lane < HH) ? lane : 0;
    float h = 0.f;
    float pre_cur = spre[myoff];
    for (int t = 0; t < NG; ++t) {
        int nt = (t + 1 < NG) ? t + 1 : t;
        float pre_next = spre[nt * HH + myoff];
        float a0 = pre_cur, a1 = 0.f, a2 = 0.f, a3 = 0.f;
        #pragma unroll
        for (int k = 0; k < HH; k += 4) {
            a0 = fmaf(bcast_lane(h, k + 0), whh[k + 0], a0);
            a1 = fmaf(bcast_lane(h, k + 1), whh[k + 1], a1);
            a2 = fmaf(bcast_lane(h, k + 2), whh[k + 2], a2);
            a3 = fmaf(bcast_lane(h, k + 3), whh[k + 3], a3);
        }
        h = tanh_fast((a0 + a1) + (a2 + a3));
        if (lane < HH) seq[t * HH + lane] = h;
        pre_cur = pre_next;
    }
}

// ---- logits = seq@W_fc^T + b_fc ; log_softmax ----
__global__ void k_out(const float* __restrict__ seq, const float* __restrict__ Wfc,
                      const float* __restrict__ bfc, float* __restrict__ out) {
    int t = blockIdx.x * 64 + threadIdx.x;
    if (t >= NG) return;
    float s[HH];
    #pragma unroll
    for (int j = 0; j < HH; ++j) s[j] = seq[t * HH + j];
    float lg[NC];
    float m = -1e30f;
    #pragma unroll
    for (int c = 0; c < NC; ++c) {
        float acc = bfc[c];
        #pragma unroll
        for (int j = 0; j < HH; ++j) acc = fmaf(s[j], Wfc[c * HH + j], acc);
        lg[c] = acc;
        m = fmaxf(m, acc);
    }
    float lse = 0.f;
    #pragma unroll
    for (int c = 0; c < NC; ++c) lse += expf(lg[c] - m);
    lse = logf(lse);
    #pragma unroll
    for (int c = 0; c < NC; ++c) out[t * NC + c] = lg[c] - m - lse;
}

extern "C" void kernel_launch(void* const* d_in, const int* in_sizes, int n_in,
                              void* d_out, int out_size, void* d_ws, size_t ws_size,
                              hipStream_t stream) {
    const float* x     = (const float*)d_in[0];
    const int*   ei    = (const int*)  d_in[1];
    const float* w     = (const float*)d_in[2];
    const int*   batch = (const int*)  d_in[3];
    const float* W0    = (const float*)d_in[5];
    const float* W1    = (const float*)d_in[6];
    const float* bconv = (const float*)d_in[7];
    const float* Wih   = (const float*)d_in[8];
    const float* Whh   = (const float*)d_in[9];
    const float* bih   = (const float*)d_in[10];
    const float* bhh   = (const float*)d_in[11];
    const float* Wfc   = (const float*)d_in[12];
    const float* bfc   = (const float*)d_in[13];
    float* out = (float*)d_out;

    float*        ws     = (float*)d_ws;
    float*        deg    = ws + OFF_DEG;
    unsigned int* cnt    = (unsigned int*)(ws + OFF_CNT);
    float*        pooled = ws + OFF_POOLED;
    float*        pre    = ws + OFF_PRE;
    float*        seq    = ws + OFF_SEQ;
    unsigned int* rowptr = (unsigned int*)(ws + OFF_ROWPTR);
    uint2*        rec    = (uint2*)(ws + OFF_REC);
    float*        y      = ws + OFF_Y;

    // zero deg | cnt | pooled (contiguous)
    hipMemsetAsync(d_ws, 0, (size_t)(OFF_POOLED + NG * FOUT) * sizeof(float), stream);

    k_degcnt<<<(NE + 255) / 256, 256, 0, stream>>>(ei, w, deg, cnt);
    k_dinv<<<(NN + 255) / 256, 256, 0, stream>>>(deg);
    k_scanptr<<<1, 1024, 0, stream>>>(cnt, rowptr);
    k_y<<<(NN * 10 + 255) / 256, 256, 0, stream>>>(x, W1, y);
    k_fill<<<(NE + 255) / 256, 256, 0, stream>>>(ei, w, deg, cnt, rec);
    k_gather_h<<<(NN * 10 + 255) / 256, 256, 0, stream>>>(rowptr, rec, y, x,
                                                          W0, bconv, batch, pooled);
    k_pre<<<(NG * HH + 255) / 256, 256, 0, stream>>>(pooled, Wih, bih, bhh, pre);
    k_scan<<<1, 64, 0, stream>>>(pre, Whh, seq);
    k_out<<<(NG + 63) / 64, 64, 0, stream>>>(seq, Wfc, bfc, out);
}

// Round 8
// 336.575 us; speedup vs baseline: 1.0683x; 1.0683x over previous
//
#include <hip/hip_runtime.h>
#include <math.h>

#define NN   50000
#define NE   800000
#define NG   500
#define FIN  80
#define FOUT 40
#define HH   20
#define NC   5

// -------- workspace layout (float offsets) --------
#define OFF_DEG    0
#define OFF_CNT    50000
#define OFF_POOLED 100000
#define OFF_PRE    120000
#define OFF_SEQ    130000
#define OFF_ROWPTR 140000
#define OFF_ESRC   190004
#define OFF_ENORM  990004
#define OFF_Y      1790004

// fast tanh: 1 - 2/(exp2(2*log2e*x)+1); exact saturation at +-inf
__device__ __forceinline__ float tanh_fast(float x) {
    float e;
    asm("v_exp_f32 %0, %1" : "=v"(e) : "v"(x * 2.8853900817779268f));
    float r;
    asm("v_rcp_f32 %0, %1" : "=v"(r) : "v"(e + 1.0f));
    return fmaf(-2.0f, r, 1.0f);
}

__device__ __forceinline__ float bcast_lane(float v, int k) {
    return __uint_as_float(__builtin_amdgcn_readlane(__float_as_uint(v), k));
}

// ---- deg[src] += w ; cnt[dst] += 1 ----
__global__ void k_degcnt(const int* __restrict__ ei, const float* __restrict__ w,
                         float* __restrict__ deg, unsigned int* __restrict__ cnt) {
    int e = blockIdx.x * 256 + threadIdx.x;
    if (e < NE) {
        atomicAdd(&deg[ei[e]], w[e]);
        atomicAdd(&cnt[ei[NE + e]], 1u);
    }
}

// ---- exclusive scan of cnt -> rowptr; cnt := exclusive prefix (fill cursor) ----
__global__ void k_scanptr(unsigned int* __restrict__ cnt, unsigned int* __restrict__ rowptr) {
    __shared__ unsigned int tot[1024];
    int tid = threadIdx.x;
    bool act = tid < 1000;
    int beg = tid * 50;
    unsigned int vals[50];
    if (act) {
        const uint2* c2 = reinterpret_cast<const uint2*>(cnt + beg);
        #pragma unroll
        for (int j = 0; j < 25; ++j) {
            uint2 v = c2[j];
            vals[j * 2 + 0] = v.x;
            vals[j * 2 + 1] = v.y;
        }
    }
    unsigned int s = 0;
    if (act) {
        #pragma unroll
        for (int j = 0; j < 50; ++j) s += vals[j];
    }
    tot[tid] = s;
    __syncthreads();
    for (int off = 1; off < 1024; off <<= 1) {
        unsigned int t = (tid >= off) ? tot[tid - off] : 0u;
        __syncthreads();
        tot[tid] += t;
        __syncthreads();
    }
    unsigned int base = (tid > 0) ? tot[tid - 1] : 0u;
    if (act) {
        #pragma unroll
        for (int j = 0; j < 50; ++j) {
            unsigned int v = vals[j];
            vals[j] = base;
            base += v;
        }
        uint2* r2 = reinterpret_cast<uint2*>(rowptr + beg);
        uint2* cw = reinterpret_cast<uint2*>(cnt + beg);
        #pragma unroll
        for (int j = 0; j < 25; ++j) {
            uint2 o = make_uint2(vals[j * 2 + 0], vals[j * 2 + 1]);
            r2[j] = o;
            cw[j] = o;
        }
    }
    if (tid == 1023) rowptr[NN] = tot[1023];
}

// ---- y = x @ W1 : thread per (node, 4-col chunk) ----
__global__ void k_y(const float* __restrict__ x, const float* __restrict__ W1,
                    float* __restrict__ y) {
    int gid = blockIdx.x * 256 + threadIdx.x;
    if (gid >= NN * 10) return;
    int n = gid / 10;
    int c = gid % 10;
    const float* xr = x + (size_t)n * FIN;
    float a0 = 0.f, a1 = 0.f, a2 = 0.f, a3 = 0.f;
    #pragma unroll 8
    for (int f = 0; f < FIN; ++f) {
        float xf = xr[f];
        const float4 wv = *reinterpret_cast<const float4*>(W1 + f * FOUT + c * 4);
        a0 = fmaf(xf, wv.x, a0); a1 = fmaf(xf, wv.y, a1);
        a2 = fmaf(xf, wv.z, a2); a3 = fmaf(xf, wv.w, a3);
    }
    float4* yo = reinterpret_cast<float4*>(y) + gid;
    *yo = make_float4(a0, a1, a2, a3);
}

// ---- fill CSR records: esrc[pos]=src, enorm[pos]=-rsqrt(deg[s])*w*rsqrt(deg[d]) ----
// (dinv computed inline from raw degrees; k_dinv pass eliminated)
__global__ void k_fill(const int* __restrict__ ei, const float* __restrict__ w,
                       const float* __restrict__ deg, unsigned int* __restrict__ cursor,
                       unsigned int* __restrict__ esrc, float* __restrict__ enorm) {
    int e = blockIdx.x * 256 + threadIdx.x;
    if (e >= NE) return;
    int s = ei[e];
    int d = ei[NE + e];
    float ds = deg[s];
    float dd = deg[d];
    float dis = (ds > 0.f) ? rsqrtf(ds) : 0.f;
    float did = (dd > 0.f) ? rsqrtf(dd) : 0.f;
    float nm = -dis * w[e] * did;
    unsigned int pos = atomicAdd(&cursor[d], 1u);
    esrc[pos] = (unsigned int)s;
    enorm[pos] = nm;
}

// ---- gather z = sum norm*y[src]; h = relu(x@W0 + b + z); pooled[g] += h ----
// (exact R6 structure: scalar loop, separate esrc/enorm streams — 93 us proven)
__global__ void k_gather_h(const unsigned int* __restrict__ rowptr,
                           const unsigned int* __restrict__ esrc,
                           const float* __restrict__ enorm,
                           const float* __restrict__ y,
                           const float* __restrict__ x,
                           const float* __restrict__ W0,
                           const float* __restrict__ bconv,
                           const int* __restrict__ batch,
                           float* __restrict__ pooled) {
    int gid = blockIdx.x * 256 + threadIdx.x;
    if (gid >= NN * 10) return;
    int n = gid / 10;
    int c = gid % 10;
    unsigned int beg = rowptr[n], end = rowptr[n + 1];
    float z0 = 0.f, z1 = 0.f, z2 = 0.f, z3 = 0.f;
    const float4* y4 = reinterpret_cast<const float4*>(y);
    for (unsigned int k = beg; k < end; ++k) {
        unsigned int s = esrc[k];
        float nm = enorm[k];
        float4 yv = y4[s * 10 + c];
        z0 = fmaf(nm, yv.x, z0); z1 = fmaf(nm, yv.y, z1);
        z2 = fmaf(nm, yv.z, z2); z3 = fmaf(nm, yv.w, z3);
    }
    const float4 bv = *reinterpret_cast<const float4*>(bconv + c * 4);
    float a0 = bv.x, a1 = bv.y, a2 = bv.z, a3 = bv.w;
    const float* xr = x + (size_t)n * FIN;
    #pragma unroll 8
    for (int f = 0; f < FIN; ++f) {
        float xf = xr[f];
        const float4 wv = *reinterpret_cast<const float4*>(W0 + f * FOUT + c * 4);
        a0 = fmaf(xf, wv.x, a0); a1 = fmaf(xf, wv.y, a1);
        a2 = fmaf(xf, wv.z, a2); a3 = fmaf(xf, wv.w, a3);
    }
    float h0 = fmaxf(a0 + z0, 0.f);
    float h1 = fmaxf(a1 + z1, 0.f);
    float h2 = fmaxf(a2 + z2, 0.f);
    float h3 = fmaxf(a3 + z3, 0.f);
    float* p = pooled + (size_t)batch[n] * FOUT + c * 4;
    atomicAdd(p + 0, h0);
    atomicAdd(p + 1, h1);
    atomicAdd(p + 2, h2);
    atomicAdd(p + 3, h3);
}

// ---- pre[t][j] = pooled[t]·W_ih[j] + b_ih[j] + b_hh[j] ----
__global__ void k_pre(const float* __restrict__ pooled, const float* __restrict__ Wih,
                      const float* __restrict__ bih, const float* __restrict__ bhh,
                      float* __restrict__ pre) {
    int gid = blockIdx.x * 256 + threadIdx.x;
    if (gid >= NG * HH) return;
    int t = gid / HH;
    int j = gid % HH;
    float acc = bih[j] + bhh[j];
    #pragma unroll
    for (int f = 0; f < FOUT; ++f)
        acc = fmaf(pooled[t * FOUT + f], Wih[j * FOUT + f], acc);
    pre[gid] = acc;
}

// ---- serial scan: h_t = tanh(pre_t + W_hh h_{t-1}) ; single wave ----
__global__ void k_scan(const float* __restrict__ pre, const float* __restrict__ Whh,
                       float* __restrict__ seq) {
    __shared__ float spre[NG * HH];          // 40 KB
    int lane = threadIdx.x;
    const float4* p4 = reinterpret_cast<const float4*>(pre);
    float4* s4 = reinterpret_cast<float4*>(spre);
    #pragma unroll
    for (int j = 0; j < 40; ++j) {
        int idx = j * 64 + lane;
        if (idx < NG * HH / 4) s4[idx] = p4[idx];
    }
    float whh[HH];
    #pragma unroll
    for (int k = 0; k < HH; ++k)
        whh[k] = (lane < HH) ? Whh[lane * HH + k] : 0.f;
    __syncthreads();
    int myoff = (lane < HH) ? lane : 0;
    float h = 0.f;
    float pre_cur = spre[myoff];
    for (int t = 0; t < NG; ++t) {
        int nt = (t + 1 < NG) ? t + 1 : t;
        float pre_next = spre[nt * HH + myoff];
        float a0 = pre_cur, a1 = 0.f, a2 = 0.f, a3 = 0.f;
        #pragma unroll
        for (int k = 0; k < HH; k += 4) {
            a0 = fmaf(bcast_lane(h, k + 0), whh[k + 0], a0);
            a1 = fmaf(bcast_lane(h, k + 1), whh[k + 1], a1);
            a2 = fmaf(bcast_lane(h, k + 2), whh[k + 2], a2);
            a3 = fmaf(bcast_lane(h, k + 3), whh[k + 3], a3);
        }
        h = tanh_fast((a0 + a1) + (a2 + a3));
        if (lane < HH) seq[t * HH + lane] = h;
        pre_cur = pre_next;
    }
}

// ---- logits = seq@W_fc^T + b_fc ; log_softmax ----
__global__ void k_out(const float* __restrict__ seq, const float* __restrict__ Wfc,
                      const float* __restrict__ bfc, float* __restrict__ out) {
    int t = blockIdx.x * 64 + threadIdx.x;
    if (t >= NG) return;
    float s[HH];
    #pragma unroll
    for (int j = 0; j < HH; ++j) s[j] = seq[t * HH + j];
    float lg[NC];
    float m = -1e30f;
    #pragma unroll
    for (int c = 0; c < NC; ++c) {
        float acc = bfc[c];
        #pragma unroll
        for (int j = 0; j < HH; ++j) acc = fmaf(s[j], Wfc[c * HH + j], acc);
        lg[c] = acc;
        m = fmaxf(m, acc);
    }
    float lse = 0.f;
    #pragma unroll
    for (int c = 0; c < NC; ++c) lse += expf(lg[c] - m);
    lse = logf(lse);
    #pragma unroll
    for (int c = 0; c < NC; ++c) out[t * NC + c] = lg[c] - m - lse;
}

extern "C" void kernel_launch(void* const* d_in, const int* in_sizes, int n_in,
                              void* d_out, int out_size, void* d_ws, size_t ws_size,
                              hipStream_t stream) {
    const float* x     = (const float*)d_in[0];
    const int*   ei    = (const int*)  d_in[1];
    const float* w     = (const float*)d_in[2];
    const int*   batch = (const int*)  d_in[3];
    const float* W0    = (const float*)d_in[5];
    const float* W1    = (const float*)d_in[6];
    const float* bconv = (const float*)d_in[7];
    const float* Wih   = (const float*)d_in[8];
    const float* Whh   = (const float*)d_in[9];
    const float* bih   = (const float*)d_in[10];
    const float* bhh   = (const float*)d_in[11];
    const float* Wfc   = (const float*)d_in[12];
    const float* bfc   = (const float*)d_in[13];
    float* out = (float*)d_out;

    float*        ws     = (float*)d_ws;
    float*        deg    = ws + OFF_DEG;
    unsigned int* cnt    = (unsigned int*)(ws + OFF_CNT);
    float*        pooled = ws + OFF_POOLED;
    float*        pre    = ws + OFF_PRE;
    float*        seq    = ws + OFF_SEQ;
    unsigned int* rowptr = (unsigned int*)(ws + OFF_ROWPTR);
    unsigned int* esrc   = (unsigned int*)(ws + OFF_ESRC);
    float*        enorm  = ws + OFF_ENORM;
    float*        y      = ws + OFF_Y;

    // zero deg | cnt | pooled (contiguous)
    hipMemsetAsync(d_ws, 0, (size_t)(OFF_POOLED + NG * FOUT) * sizeof(float), stream);

    k_degcnt<<<(NE + 255) / 256, 256, 0, stream>>>(ei, w, deg, cnt);
    k_scanptr<<<1, 1024, 0, stream>>>(cnt, rowptr);
    k_y<<<(NN * 10 + 255) / 256, 256, 0, stream>>>(x, W1, y);
    k_fill<<<(NE + 255) / 256, 256, 0, stream>>>(ei, w, deg, cnt, esrc, enorm);
    k_gather_h<<<(NN * 10 + 255) / 256, 256, 0, stream>>>(rowptr, esrc, enorm, y, x,
                                                          W0, bconv, batch, pooled);
    k_pre<<<(NG * HH + 255) / 256, 256, 0, stream>>>(pooled, Wih, bih, bhh, pre);
    k_scan<<<1, 64, 0, stream>>>(pre, Whh, seq);
    k_out<<<(NG + 63) / 64, 64, 0, stream>>>(seq, Wfc, bfc, out);
}

// Round 9
// 295.393 us; speedup vs baseline: 1.2173x; 1.1394x over previous
//
#include <hip/hip_runtime.h>
#include <math.h>

#define NN   50000
#define NE   800000
#define NG   500
#define FIN  80
#define FOUT 40
#define HH   20
#define NC   5

// -------- workspace layout (float offsets) --------
#define OFF_DEG    0
#define OFF_CNT    50000
#define OFF_POOLED 100000
#define OFF_PRE    120000
#define OFF_SEQ    130000
#define OFF_ROWPTR 140000
#define OFF_ESRC   190004
#define OFF_ENORM  990004
#define OFF_Y      1790004          // bf16[NN*40] = 4 MB; byte off %8==0

// fast tanh: 1 - 2/(exp2(2*log2e*x)+1); exact saturation at +-inf
__device__ __forceinline__ float tanh_fast(float x) {
    float e;
    asm("v_exp_f32 %0, %1" : "=v"(e) : "v"(x * 2.8853900817779268f));
    float r;
    asm("v_rcp_f32 %0, %1" : "=v"(r) : "v"(e + 1.0f));
    return fmaf(-2.0f, r, 1.0f);
}

__device__ __forceinline__ float bcast_lane(float v, int k) {
    return __uint_as_float(__builtin_amdgcn_readlane(__float_as_uint(v), k));
}

__device__ __forceinline__ unsigned short bf16_rn(float f) {
    unsigned u = __float_as_uint(f);
    return (unsigned short)((u + 0x7fffu + ((u >> 16) & 1u)) >> 16);
}
__device__ __forceinline__ float bf16_to_f32(unsigned short h) {
    return __uint_as_float((unsigned)h << 16);
}

// ---- deg[src] += w ; cnt[dst] += 1 ----
__global__ void k_degcnt(const int* __restrict__ ei, const float* __restrict__ w,
                         float* __restrict__ deg, unsigned int* __restrict__ cnt) {
    int e = blockIdx.x * 256 + threadIdx.x;
    if (e < NE) {
        atomicAdd(&deg[ei[e]], w[e]);
        atomicAdd(&cnt[ei[NE + e]], 1u);
    }
}

// ---- exclusive scan of cnt -> rowptr; cnt := exclusive prefix (fill cursor) ----
__global__ void k_scanptr(unsigned int* __restrict__ cnt, unsigned int* __restrict__ rowptr) {
    __shared__ unsigned int tot[1024];
    int tid = threadIdx.x;
    bool act = tid < 1000;
    int beg = tid * 50;
    unsigned int vals[50];
    if (act) {
        const uint2* c2 = reinterpret_cast<const uint2*>(cnt + beg);
        #pragma unroll
        for (int j = 0; j < 25; ++j) {
            uint2 v = c2[j];
            vals[j * 2 + 0] = v.x;
            vals[j * 2 + 1] = v.y;
        }
    }
    unsigned int s = 0;
    if (act) {
        #pragma unroll
        for (int j = 0; j < 50; ++j) s += vals[j];
    }
    tot[tid] = s;
    __syncthreads();
    for (int off = 1; off < 1024; off <<= 1) {
        unsigned int t = (tid >= off) ? tot[tid - off] : 0u;
        __syncthreads();
        tot[tid] += t;
        __syncthreads();
    }
    unsigned int base = (tid > 0) ? tot[tid - 1] : 0u;
    if (act) {
        #pragma unroll
        for (int j = 0; j < 50; ++j) {
            unsigned int v = vals[j];
            vals[j] = base;
            base += v;
        }
        uint2* r2 = reinterpret_cast<uint2*>(rowptr + beg);
        uint2* cw = reinterpret_cast<uint2*>(cnt + beg);
        #pragma unroll
        for (int j = 0; j < 25; ++j) {
            uint2 o = make_uint2(vals[j * 2 + 0], vals[j * 2 + 1]);
            r2[j] = o;
            cw[j] = o;
        }
    }
    if (tid == 1023) rowptr[NN] = tot[1023];
}

// ---- y = bf16(x @ W1) : thread per (node, 4-col chunk) ----
__global__ void k_y(const float* __restrict__ x, const float* __restrict__ W1,
                    unsigned short* __restrict__ y) {
    int gid = blockIdx.x * 256 + threadIdx.x;
    if (gid >= NN * 10) return;
    int n = gid / 10;
    int c = gid % 10;
    const float* xr = x + (size_t)n * FIN;
    float a0 = 0.f, a1 = 0.f, a2 = 0.f, a3 = 0.f;
    #pragma unroll 8
    for (int f = 0; f < FIN; ++f) {
        float xf = xr[f];
        const float4 wv = *reinterpret_cast<const float4*>(W1 + f * FOUT + c * 4);
        a0 = fmaf(xf, wv.x, a0); a1 = fmaf(xf, wv.y, a1);
        a2 = fmaf(xf, wv.z, a2); a3 = fmaf(xf, wv.w, a3);
    }
    ushort4 o;
    o.x = bf16_rn(a0); o.y = bf16_rn(a1); o.z = bf16_rn(a2); o.w = bf16_rn(a3);
    *reinterpret_cast<ushort4*>(y + (size_t)gid * 4) = o;
}

// ---- fill CSR records: esrc[pos]=src, enorm[pos]=-rsqrt(deg[s])*w*rsqrt(deg[d]) ----
__global__ void k_fill(const int* __restrict__ ei, const float* __restrict__ w,
                       const float* __restrict__ deg, unsigned int* __restrict__ cursor,
                       unsigned int* __restrict__ esrc, float* __restrict__ enorm) {
    int e = blockIdx.x * 256 + threadIdx.x;
    if (e >= NE) return;
    int s = ei[e];
    int d = ei[NE + e];
    float ds = deg[s];
    float dd = deg[d];
    float dis = (ds > 0.f) ? rsqrtf(ds) : 0.f;
    float did = (dd > 0.f) ? rsqrtf(dd) : 0.f;
    float nm = -dis * w[e] * did;
    unsigned int pos = atomicAdd(&cursor[d], 1u);
    esrc[pos] = (unsigned int)s;
    enorm[pos] = nm;
}

// ---- gather z = sum norm*y[src]; h = relu(x@W0 + b + z);
//      per-block LDS pool accumulation, then flush to global pooled ----
__global__ void k_gather_h(const unsigned int* __restrict__ rowptr,
                           const unsigned int* __restrict__ esrc,
                           const float* __restrict__ enorm,
                           const unsigned short* __restrict__ y,
                           const float* __restrict__ x,
                           const float* __restrict__ W0,
                           const float* __restrict__ bconv,
                           const int* __restrict__ batch,
                           float* __restrict__ pooled) {
    __shared__ float lpool[32 * FOUT];      // block spans <=27 nodes -> <=27 graphs
    int tid = threadIdx.x;
    int b0 = blockIdx.x * 256;
    #pragma unroll
    for (int i = tid; i < 32 * FOUT; i += 256) lpool[i] = 0.f;
    int g_lo = batch[b0 / 10];
    __syncthreads();

    int gid = b0 + tid;
    if (gid < NN * 10) {
        int n = gid / 10;
        int c = gid % 10;
        unsigned int beg = rowptr[n], end = rowptr[n + 1];
        float z0 = 0.f, z1 = 0.f, z2 = 0.f, z3 = 0.f;
        const ushort4* y4 = reinterpret_cast<const ushort4*>(y);
        for (unsigned int k = beg; k < end; ++k) {
            unsigned int s = esrc[k];
            float nm = enorm[k];
            ushort4 yv = y4[s * 10 + c];
            z0 = fmaf(nm, bf16_to_f32(yv.x), z0);
            z1 = fmaf(nm, bf16_to_f32(yv.y), z1);
            z2 = fmaf(nm, bf16_to_f32(yv.z), z2);
            z3 = fmaf(nm, bf16_to_f32(yv.w), z3);
        }
        const float4 bv = *reinterpret_cast<const float4*>(bconv + c * 4);
        float a0 = bv.x, a1 = bv.y, a2 = bv.z, a3 = bv.w;
        const float* xr = x + (size_t)n * FIN;
        #pragma unroll 8
        for (int f = 0; f < FIN; ++f) {
            float xf = xr[f];
            const float4 wv = *reinterpret_cast<const float4*>(W0 + f * FOUT + c * 4);
            a0 = fmaf(xf, wv.x, a0); a1 = fmaf(xf, wv.y, a1);
            a2 = fmaf(xf, wv.z, a2); a3 = fmaf(xf, wv.w, a3);
        }
        float h0 = fmaxf(a0 + z0, 0.f);
        float h1 = fmaxf(a1 + z1, 0.f);
        float h2 = fmaxf(a2 + z2, 0.f);
        float h3 = fmaxf(a3 + z3, 0.f);
        float* lp = lpool + (batch[n] - g_lo) * FOUT + c * 4;
        atomicAdd(lp + 0, h0);
        atomicAdd(lp + 1, h1);
        atomicAdd(lp + 2, h2);
        atomicAdd(lp + 3, h3);
    }
    __syncthreads();
    int n_hi = (b0 + 255) / 10;
    if (n_hi > NN - 1) n_hi = NN - 1;
    int span = batch[n_hi] - g_lo + 1;
    for (int i = tid; i < span * FOUT; i += 256) {
        float v = lpool[i];
        if (v != 0.f) atomicAdd(&pooled[(size_t)g_lo * FOUT + i], v);
    }
}

// ---- pre[t][j] = pooled[t]·W_ih[j] + b_ih[j] + b_hh[j] ----
__global__ void k_pre(const float* __restrict__ pooled, const float* __restrict__ Wih,
                      const float* __restrict__ bih, const float* __restrict__ bhh,
                      float* __restrict__ pre) {
    int gid = blockIdx.x * 256 + threadIdx.x;
    if (gid >= NG * HH) return;
    int t = gid / HH;
    int j = gid % HH;
    float acc = bih[j] + bhh[j];
    #pragma unroll
    for (int f = 0; f < FOUT; ++f)
        acc = fmaf(pooled[t * FOUT + f], Wih[j * FOUT + f], acc);
    pre[gid] = acc;
}

// ---- serial scan: h_t = tanh(pre_t + W_hh h_{t-1}) ; single wave ----
__global__ void k_scan(const float* __restrict__ pre, const float* __restrict__ Whh,
                       float* __restrict__ seq) {
    __shared__ float spre[NG * HH];          // 40 KB
    int lane = threadIdx.x;
    const float4* p4 = reinterpret_cast<const float4*>(pre);
    float4* s4 = reinterpret_cast<float4*>(spre);
    #pragma unroll
    for (int j = 0; j < 40; ++j) {
        int idx = j * 64 + lane;
        if (idx < NG * HH / 4) s4[idx] = p4[idx];
    }
    float whh[HH];
    #pragma unroll
    for (int k = 0; k < HH; ++k)
        whh[k] = (lane < HH) ? Whh[lane * HH + k] : 0.f;
    __syncthreads();
    int myoff = (lane < HH) ? lane : 0;
    float h = 0.f;
    float pre_cur = spre[myoff];
    for (int t = 0; t < NG; ++t) {
        int nt = (t + 1 < NG) ? t + 1 : t;
        float pre_next = spre[nt * HH + myoff];
        float a0 = pre_cur, a1 = 0.f, a2 = 0.f, a3 = 0.f;
        #pragma unroll
        for (int k = 0; k < HH; k += 4) {
            a0 = fmaf(bcast_lane(h, k + 0), whh[k + 0], a0);
            a1 = fmaf(bcast_lane(h, k + 1), whh[k + 1], a1);
            a2 = fmaf(bcast_lane(h, k + 2), whh[k + 2], a2);
            a3 = fmaf(bcast_lane(h, k + 3), whh[k + 3], a3);
        }
        h = tanh_fast((a0 + a1) + (a2 + a3));
        if (lane < HH) seq[t * HH + lane] = h;
        pre_cur = pre_next;
    }
}

// ---- logits = seq@W_fc^T + b_fc ; log_softmax ----
__global__ void k_out(const float* __restrict__ seq, const float* __restrict__ Wfc,
                      const float* __restrict__ bfc, float* __restrict__ out) {
    int t = blockIdx.x * 64 + threadIdx.x;
    if (t >= NG) return;
    float s[HH];
    #pragma unroll
    for (int j = 0; j < HH; ++j) s[j] = seq[t * HH + j];
    float lg[NC];
    float m = -1e30f;
    #pragma unroll
    for (int c = 0; c < NC; ++c) {
        float acc = bfc[c];
        #pragma unroll
        for (int j = 0; j < HH; ++j) acc = fmaf(s[j], Wfc[c * HH + j], acc);
        lg[c] = acc;
        m = fmaxf(m, acc);
    }
    float lse = 0.f;
    #pragma unroll
    for (int c = 0; c < NC; ++c) lse += expf(lg[c] - m);
    lse = logf(lse);
    #pragma unroll
    for (int c = 0; c < NC; ++c) out[t * NC + c] = lg[c] - m - lse;
}

extern "C" void kernel_launch(void* const* d_in, const int* in_sizes, int n_in,
                              void* d_out, int out_size, void* d_ws, size_t ws_size,
                              hipStream_t stream) {
    const float* x     = (const float*)d_in[0];
    const int*   ei    = (const int*)  d_in[1];
    const float* w     = (const float*)d_in[2];
    const int*   batch = (const int*)  d_in[3];
    const float* W0    = (const float*)d_in[5];
    const float* W1    = (const float*)d_in[6];
    const float* bconv = (const float*)d_in[7];
    const float* Wih   = (const float*)d_in[8];
    const float* Whh   = (const float*)d_in[9];
    const float* bih   = (const float*)d_in[10];
    const float* bhh   = (const float*)d_in[11];
    const float* Wfc   = (const float*)d_in[12];
    const float* bfc   = (const float*)d_in[13];
    float* out = (float*)d_out;

    float*          ws     = (float*)d_ws;
    float*          deg    = ws + OFF_DEG;
    unsigned int*   cnt    = (unsigned int*)(ws + OFF_CNT);
    float*          pooled = ws + OFF_POOLED;
    float*          pre    = ws + OFF_PRE;
    float*          seq    = ws + OFF_SEQ;
    unsigned int*   rowptr = (unsigned int*)(ws + OFF_ROWPTR);
    unsigned int*   esrc   = (unsigned int*)(ws + OFF_ESRC);
    float*          enorm  = ws + OFF_ENORM;
    unsigned short* y      = (unsigned short*)(ws + OFF_Y);

    // zero deg | cnt | pooled (contiguous)
    hipMemsetAsync(d_ws, 0, (size_t)(OFF_POOLED + NG * FOUT) * sizeof(float), stream);

    k_degcnt<<<(NE + 255) / 256, 256, 0, stream>>>(ei, w, deg, cnt);
    k_scanptr<<<1, 1024, 0, stream>>>(cnt, rowptr);
    k_y<<<(NN * 10 + 255) / 256, 256, 0, stream>>>(x, W1, y);
    k_fill<<<(NE + 255) / 256, 256, 0, stream>>>(ei, w, deg, cnt, esrc, enorm);
    k_gather_h<<<(NN * 10 + 255) / 256, 256, 0, stream>>>(rowptr, esrc, enorm, y, x,
                                                          W0, bconv, batch, pooled);
    k_pre<<<(NG * HH + 255) / 256, 256, 0, stream>>>(pooled, Wih, bih, bhh, pre);
    k_scan<<<1, 64, 0, stream>>>(pre, Whh, seq);
    k_out<<<(NG + 63) / 64, 64, 0, stream>>>(seq, Wfc, bfc, out);
}